// Round 1
// 212.837 us; speedup vs baseline: 1.0240x; 1.0240x over previous
//
#include <hip/hip_runtime.h>
#include <stdint.h>

#define NNODES 200000
#define BNODES 40000
#define DEG    16
#define DFEAT  128
#define DOUT   256
#define NCLS   128
#define TILE   32   // nodes per block

typedef __attribute__((ext_vector_type(8))) __bf16 bf16x8;
typedef __attribute__((ext_vector_type(4))) float  floatx4;

// round-to-nearest-even fp32 -> bf16 bits
__device__ __forceinline__ uint32_t f2bf(float f) {
  uint32_t x = __float_as_uint(f);
  return ((x + 0x7fffu + ((x >> 16) & 1u)) >> 16) & 0xffffu;
}

__global__ void cvt_weights(const float* __restrict__ W1, const float* __restrict__ W3,
                            uint16_t* __restrict__ w1b, uint16_t* __restrict__ w3b) {
  int i = blockIdx.x * 256 + threadIdx.x;
  if (i < DOUT * 2 * DFEAT) w1b[i] = (uint16_t)f2bf(W1[i]);
  if (i < NCLS * DOUT)      w3b[i] = (uint16_t)f2bf(W3[i]);
}

__global__ __launch_bounds__(256, 4) void sage_fused(
    const int* __restrict__ inputs, const int* __restrict__ nbr,
    const float* __restrict__ feat,
    const uint16_t* __restrict__ w1b, const float* __restrict__ b1,
    const uint16_t* __restrict__ w3b, const float* __restrict__ b3,
    float* __restrict__ out) {
  // embL (phases 1-2) and lgL (phases 3-4) alias: LDS 50688 -> 33792 B => 4 blocks/CU
  __shared__ __align__(16) unsigned char smemA[TILE * 264 * 2];   // 16896 B
  __shared__ __align__(16) uint16_t hL[TILE][264];                // 16896 B
  uint16_t (*embL)[264] = (uint16_t (*)[264])smemA;
  float    (*lgL)[132]  = (float    (*)[132])smemA;

  const int tid  = threadIdx.x;
  const int w    = tid >> 6;       // wave 0..3
  const int lane = tid & 63;
  const int quad = lane >> 4;
  const int l16  = lane & 15;

  // ---------------- Phase 1: gather + segment-mean -> emb (bf16 in LDS) ----
  // Half-wave per node: 32 lanes x float4 = one 512B feature row per load.
  // Per node-pair: 16 neighbor loads + self + 4 id loads issued as one
  // independent batch (~17 KB/wave in flight) -> deep MLP for the random gather.
  {
    const int h   = lane >> 5;     // half 0/1
    const int l32 = lane & 31;
    const int col = l32 * 4;       // dims 4l..4l+3
    const int nodeBase = blockIdx.x * TILE + w * 8;
    const float* fb = feat + col;
#pragma unroll
    for (int p = 0; p < 4; ++p) {
      const int node = nodeBase + p * 2 + h;
      const int row  = w * 8 + p * 2 + h;
      const int* nb  = nbr + node * DEG;
      const int4 i0 = *(const int4*)(nb + 0);
      const int4 i1 = *(const int4*)(nb + 4);
      const int4 i2 = *(const int4*)(nb + 8);
      const int4 i3 = *(const int4*)(nb + 12);
      const int self = inputs[node];
#define LDN(name, idx) const floatx4 name = *(const floatx4*)(fb + (size_t)(idx) * DFEAT)
      LDN(v0,  i0.x); LDN(v1,  i0.y); LDN(v2,  i0.z); LDN(v3,  i0.w);
      LDN(v4,  i1.x); LDN(v5,  i1.y); LDN(v6,  i1.z); LDN(v7,  i1.w);
      LDN(v8,  i2.x); LDN(v9,  i2.y); LDN(v10, i2.z); LDN(v11, i2.w);
      LDN(v12, i3.x); LDN(v13, i3.y); LDN(v14, i3.z); LDN(v15, i3.w);
      LDN(sv, self);
#undef LDN
      const floatx4 s = (((v0 + v1) + (v2 + v3)) + ((v4 + v5) + (v6 + v7)))
                      + (((v8 + v9) + (v10 + v11)) + ((v12 + v13) + (v14 + v15)));
      const floatx4 m = s * 0.0625f;
      uint2 selfp, meanp;
      selfp.x = f2bf(sv.x) | (f2bf(sv.y) << 16);
      selfp.y = f2bf(sv.z) | (f2bf(sv.w) << 16);
      meanp.x = f2bf(m.x) | (f2bf(m.y) << 16);
      meanp.y = f2bf(m.z) | (f2bf(m.w) << 16);
      *(uint2*)&embL[row][col]         = selfp;   // self dims 4l..4l+3
      *(uint2*)&embL[row][DFEAT + col] = meanp;   // mean dims 128+4l..
    }
  }
  __syncthreads();

  const int kq = quad * 8;

  // ---------------- Phase 2: h = relu(emb @ W1^T + b1), bf16 -> LDS --------
  {
    floatx4 acc[2][4];
#pragma unroll
    for (int mt = 0; mt < 2; ++mt)
#pragma unroll
      for (int ot = 0; ot < 4; ++ot) {
        floatx4 z = {0.f, 0.f, 0.f, 0.f};
        acc[mt][ot] = z;
      }
#pragma unroll
    for (int kt = 0; kt < 8; ++kt) {
      const int k0 = kt * 32 + kq;
      const bf16x8 a0 = *(const bf16x8*)&embL[l16][k0];
      const bf16x8 a1 = *(const bf16x8*)&embL[16 + l16][k0];
#pragma unroll
      for (int ot = 0; ot < 4; ++ot) {
        const int o = (w * 4 + ot) * 16 + l16;
        const bf16x8 b = *(const bf16x8*)(w1b + o * 256 + k0);
        acc[0][ot] = __builtin_amdgcn_mfma_f32_16x16x32_bf16(a0, b, acc[0][ot], 0, 0, 0);
        acc[1][ot] = __builtin_amdgcn_mfma_f32_16x16x32_bf16(a1, b, acc[1][ot], 0, 0, 0);
      }
    }
#pragma unroll
    for (int ot = 0; ot < 4; ++ot) {
      const int o = (w * 4 + ot) * 16 + l16;
      const float bias = b1[o];
#pragma unroll
      for (int mt = 0; mt < 2; ++mt)
#pragma unroll
        for (int r = 0; r < 4; ++r) {
          float v = acc[mt][ot][r] + bias;
          v = fmaxf(v, 0.f);
          hL[mt * 16 + quad * 4 + r][o] = (uint16_t)f2bf(v);
        }
    }
  }
  __syncthreads();

  // ---------------- Phase 3: logits = h @ W3^T + b3 -> LDS fp32 ------------
  // (writes lgL, which aliases embL -- embL is dead after phase 2's barrier)
  {
    floatx4 acc2[2][2];
#pragma unroll
    for (int mt = 0; mt < 2; ++mt)
#pragma unroll
      for (int ct = 0; ct < 2; ++ct) {
        floatx4 z = {0.f, 0.f, 0.f, 0.f};
        acc2[mt][ct] = z;
      }
#pragma unroll
    for (int kt = 0; kt < 8; ++kt) {
      const int k0 = kt * 32 + kq;
      const bf16x8 a0 = *(const bf16x8*)&hL[l16][k0];
      const bf16x8 a1 = *(const bf16x8*)&hL[16 + l16][k0];
#pragma unroll
      for (int ct = 0; ct < 2; ++ct) {
        const int c = (w * 2 + ct) * 16 + l16;
        const bf16x8 b = *(const bf16x8*)(w3b + c * 256 + k0);
        acc2[0][ct] = __builtin_amdgcn_mfma_f32_16x16x32_bf16(a0, b, acc2[0][ct], 0, 0, 0);
        acc2[1][ct] = __builtin_amdgcn_mfma_f32_16x16x32_bf16(a1, b, acc2[1][ct], 0, 0, 0);
      }
    }
#pragma unroll
    for (int ct = 0; ct < 2; ++ct) {
      const int c = (w * 2 + ct) * 16 + l16;
      const float bias = b3[c];
#pragma unroll
      for (int mt = 0; mt < 2; ++mt)
#pragma unroll
        for (int r = 0; r < 4; ++r)
          lgL[mt * 16 + quad * 4 + r][c] = acc2[mt][ct][r] + bias;
    }
  }
  __syncthreads();

  // ---------------- Phase 4: row L2-normalize + store ----------------------
  {
    const int nr  = tid >> 3;       // node row 0..31
    const int sub = tid & 7;        // 8 threads per row, 16 cols each
    const float* lrow = &lgL[nr][sub * 16];
    float4 v0 = *(const float4*)(lrow + 0);
    float4 v1 = *(const float4*)(lrow + 4);
    float4 v2 = *(const float4*)(lrow + 8);
    float4 v3 = *(const float4*)(lrow + 12);
    float ss = v0.x * v0.x + v0.y * v0.y + v0.z * v0.z + v0.w * v0.w
             + v1.x * v1.x + v1.y * v1.y + v1.z * v1.z + v1.w * v1.w
             + v2.x * v2.x + v2.y * v2.y + v2.z * v2.z + v2.w * v2.w
             + v3.x * v3.x + v3.y * v3.y + v3.z * v3.z + v3.w * v3.w;
    ss += __shfl_xor(ss, 1);
    ss += __shfl_xor(ss, 2);
    ss += __shfl_xor(ss, 4);
    const float scale = 1.f / fmaxf(sqrtf(ss), 1e-12f);
    v0.x *= scale; v0.y *= scale; v0.z *= scale; v0.w *= scale;
    v1.x *= scale; v1.y *= scale; v1.z *= scale; v1.w *= scale;
    v2.x *= scale; v2.y *= scale; v2.z *= scale; v2.w *= scale;
    v3.x *= scale; v3.y *= scale; v3.z *= scale; v3.w *= scale;
    float* op = out + ((size_t)(blockIdx.x * TILE + nr)) * NCLS + sub * 16;
    *(float4*)(op + 0)  = v0;
    *(float4*)(op + 4)  = v1;
    *(float4*)(op + 8)  = v2;
    *(float4*)(op + 12) = v3;
  }
}

extern "C" void kernel_launch(void* const* d_in, const int* in_sizes, int n_in,
                              void* d_out, int out_size, void* d_ws, size_t ws_size,
                              hipStream_t stream) {
  const int*   inputs = (const int*)d_in[0];
  const int*   nbr    = (const int*)d_in[1];
  // d_in[2] segment_ids: regular repeat(arange(B), 16) -> implicit, unused
  const float* feat   = (const float*)d_in[3];
  const float* W1     = (const float*)d_in[4];
  const float* b1     = (const float*)d_in[5];
  const float* W3     = (const float*)d_in[6];
  const float* b3     = (const float*)d_in[7];

  uint16_t* w1b = (uint16_t*)d_ws;                 // 256*256 bf16
  uint16_t* w3b = w1b + DOUT * 2 * DFEAT;          // 128*256 bf16 (total 192 KiB ws)

  cvt_weights<<<(DOUT * 2 * DFEAT) / 256, 256, 0, stream>>>(W1, W3, w1b, w3b);
  sage_fused<<<BNODES / TILE, 256, 0, stream>>>(inputs, nbr, feat, w1b, b1, w3b, b3,
                                                (float*)d_out);
}